// Round 1
// baseline (10541.353 us; speedup 1.0000x reference)
//
#include <hip/hip_runtime.h>
#include <hip/hip_bf16.h>

// LSTM encoder: B=64, L=2048, D=256, 4D=1024, VOCAB=6000
// Design: 32 persistent WGs = 4 row-groups(16 rows) x 8 col-WGs(32 d-channels).
// Weights [U;W] (K=512 fused: h-part + x-part) held permanently in VGPRs as
// MFMA B-fragments. Per step: x-MFMAs (no dependency) -> flag spin-wait ->
// h-MFMAs -> gates via LDS -> elementwise LSTM (c,h in regs) -> publish h slice.
// h buffer double-buffered; flags give a one-step lag so no read/write race.

#define B_     64
#define L_     2048
#define D_     256
#define G4_    1024
#define VOCAB_ 6000

typedef short s16x8 __attribute__((ext_vector_type(8)));
typedef float f32x4 __attribute__((ext_vector_type(4)));

// ---- ws layout (bytes) ----
#define OFF_EMBB   0u                       // VOCAB*D bf16 = 3,072,000
#define OFF_WT     3072000u                 // 4D x D bf16 (W^T) = 524,288
#define OFF_UT     3596288u                 // 4D x D bf16 (U^T) = 524,288
#define OFF_HBUF   4120576u                 // 2 x (64 x 256) bf16 = 65,536
#define OFF_FLAGS  4186112u                 // 4 groups x 8 flags x 64B = 2048
#define WS_NEED    4188160u

__global__ void prep_kernel(const float* __restrict__ emb,
                            const float* __restrict__ W,
                            const float* __restrict__ U,
                            __hip_bfloat16* __restrict__ embb,
                            __hip_bfloat16* __restrict__ Wt,
                            __hip_bfloat16* __restrict__ Ut) {
  const int stride = gridDim.x * blockDim.x;
  const int i0 = blockIdx.x * blockDim.x + threadIdx.x;
  for (int i = i0; i < VOCAB_ * D_; i += stride)
    embb[i] = __float2bfloat16(emb[i]);
  for (int i = i0; i < D_ * G4_; i += stride) {
    int k = i >> 10;            // row in W/U (0..255)
    int n = i & (G4_ - 1);      // col (0..1023)
    Wt[n * D_ + k] = __float2bfloat16(W[i]);
    Ut[n * D_ + k] = __float2bfloat16(U[i]);
  }
}

__global__ __launch_bounds__(256, 1)
void lstm_kernel(const int* __restrict__ ctx,
                 const float* __restrict__ bias,
                 const __hip_bfloat16* __restrict__ embb,
                 const __hip_bfloat16* __restrict__ Wt,
                 const __hip_bfloat16* __restrict__ Ut,
                 __hip_bfloat16* __restrict__ hbuf,
                 unsigned* __restrict__ flags,
                 float* __restrict__ out) {
  const int wg  = blockIdx.x;
  const int g   = wg & 3;        // row group: batch rows [g*16, g*16+16)
  const int cB  = wg >> 2;       // d-block: d in [cB*32, cB*32+32)
  const int tid = threadIdx.x;
  const int v   = tid >> 6;      // wave index == gate index (i,f,cand,o)
  const int l   = tid & 63;
  const int l15 = l & 15, lhi = l >> 4;

  __shared__ int   s_tok[16];
  __shared__ float s_g[4][16][33];   // [gate][row][d_local], +1 pad
  __shared__ float s_b[4][32];

  if (tid < 128) {
    int q = tid >> 5, dl = tid & 31;
    s_b[q][dl] = bias[q * D_ + cB * 32 + dl];
  }

  // ---- preload weight B-fragments: wave v owns gate v, 2 n-tiles of 16 cols.
  // B[k][n] frag layout: lane l holds k = kk*32 + (l>>4)*8 + j (j=0..7), n = n0 + (l&15).
  // kk 0..7 -> U (h part, k<256); kk 8..15 -> W (x part).
  s16x8 bfr[16][2];
  {
    const int nbase = v * D_ + cB * 32;
#pragma unroll
    for (int nt = 0; nt < 2; ++nt) {
      const int n = nbase + nt * 16 + l15;
      const __hip_bfloat16* up = Ut + n * D_ + lhi * 8;
      const __hip_bfloat16* wp = Wt + n * D_ + lhi * 8;
#pragma unroll
      for (int kk = 0; kk < 8; ++kk) {
        bfr[kk][nt]     = *(const s16x8*)(up + kk * 32);
        bfr[kk + 8][nt] = *(const s16x8*)(wp + kk * 32);
      }
    }
  }

  // elementwise ownership: thread -> (row em, d_local ed, ed+1)
  const int em = tid >> 4;
  const int ed = (tid & 15) * 2;
  float c0 = 0.f, c1 = 0.f, hp0 = 0.f, hp1 = 0.f;

  unsigned* myflags = flags + g * 8 * 16;   // 8 flags, 64B apart
  const int row0 = g * 16;

  for (int t = 0; t < L_; ++t) {
    __syncthreads();                       // protects s_tok / s_g reuse
    if (tid < 16) s_tok[tid] = ctx[(row0 + tid) * L_ + t];
    __syncthreads();

    // ---- x part (independent of h): A[m][k] = emb[tok[m]][k-256]
    const int tok = s_tok[l15];
    const __hip_bfloat16* xp = embb + tok * D_ + lhi * 8;
    s16x8 af[8];
#pragma unroll
    for (int kk = 0; kk < 8; ++kk)
      af[kk] = *(const s16x8*)(xp + kk * 32);

    f32x4 acc0 = {0.f, 0.f, 0.f, 0.f}, acc1 = {0.f, 0.f, 0.f, 0.f};
#pragma unroll
    for (int kk = 0; kk < 8; ++kk) {
      acc0 = __builtin_amdgcn_mfma_f32_16x16x32_bf16(af[kk], bfr[kk + 8][0], acc0, 0, 0, 0);
      acc1 = __builtin_amdgcn_mfma_f32_16x16x32_bf16(af[kk], bfr[kk + 8][1], acc1, 0, 0, 0);
    }

    // ---- h part: wait for all 8 col-WGs of this group to publish h(t-1)
    if (t > 0) {
      const unsigned want = (unsigned)t;
      while (true) {
        unsigned f = __hip_atomic_load(&myflags[(l & 7) * 16], __ATOMIC_RELAXED,
                                       __HIP_MEMORY_SCOPE_AGENT);
        if (__all((int)(f >= want))) break;
      }
      __builtin_amdgcn_fence(__ATOMIC_ACQUIRE, "agent");
      const __hip_bfloat16* hp = hbuf + ((t - 1) & 1) * (B_ * D_) + (row0 + l15) * D_ + lhi * 8;
#pragma unroll
      for (int kk = 0; kk < 8; ++kk)
        af[kk] = *(const s16x8*)(hp + kk * 32);
#pragma unroll
      for (int kk = 0; kk < 8; ++kk) {
        acc0 = __builtin_amdgcn_mfma_f32_16x16x32_bf16(af[kk], bfr[kk][0], acc0, 0, 0, 0);
        acc1 = __builtin_amdgcn_mfma_f32_16x16x32_bf16(af[kk], bfr[kk][1], acc1, 0, 0, 0);
      }
    }

    // ---- gates to LDS (C/D layout: row=(l>>4)*4+r, col=l&15)
#pragma unroll
    for (int r = 0; r < 4; ++r) {
      s_g[v][lhi * 4 + r][l15]      = acc0[r];
      s_g[v][lhi * 4 + r][16 + l15] = acc1[r];
    }
    __syncthreads();

    // ---- elementwise LSTM update (2 elements per thread)
    {
      const int tokm = s_tok[em];
      float gi0 = s_g[0][em][ed]     + s_b[0][ed];
      float gi1 = s_g[0][em][ed + 1] + s_b[0][ed + 1];
      float gf0 = s_g[1][em][ed]     + s_b[1][ed];
      float gf1 = s_g[1][em][ed + 1] + s_b[1][ed + 1];
      float gc0 = s_g[2][em][ed]     + s_b[2][ed];
      float gc1 = s_g[2][em][ed + 1] + s_b[2][ed + 1];
      float go0 = s_g[3][em][ed]     + s_b[3][ed];
      float go1 = s_g[3][em][ed + 1] + s_b[3][ed + 1];
      float i0 = 1.f / (1.f + expf(-gi0)), i1 = 1.f / (1.f + expf(-gi1));
      float f0 = 1.f / (1.f + expf(-gf0)), f1 = 1.f / (1.f + expf(-gf1));
      float o0 = 1.f / (1.f + expf(-go0)), o1 = 1.f / (1.f + expf(-go1));
      float cn0 = f0 * c0 + i0 * tanhf(gc0);
      float cn1 = f1 * c1 + i1 * tanhf(gc1);
      float hn0 = o0 * tanhf(cn0);
      float hn1 = o1 * tanhf(cn1);
      const bool upd = (tokm != 0);
      c0  = upd ? cn0 : c0;   c1  = upd ? cn1 : c1;
      hp0 = upd ? hn0 : hp0;  hp1 = upd ? hn1 : hp1;
      const int orow = row0 + em;
      float* op = out + ((size_t)orow * L_ + t) * D_ + cB * 32 + ed;
      op[0] = hp0;
      op[1] = hp1;
      __hip_bfloat16* hw = hbuf + (t & 1) * (B_ * D_) + orow * D_ + cB * 32 + ed;
      hw[0] = __float2bfloat16(hp0);
      hw[1] = __float2bfloat16(hp1);
    }

    __syncthreads();   // drains each wave's vmem before publish
    if (tid == 0) {
      __builtin_amdgcn_fence(__ATOMIC_RELEASE, "agent");
      __hip_atomic_store(&myflags[cB * 16], (unsigned)(t + 1), __ATOMIC_RELAXED,
                         __HIP_MEMORY_SCOPE_AGENT);
    }
  }
}

extern "C" void kernel_launch(void* const* d_in, const int* in_sizes, int n_in,
                              void* d_out, int out_size, void* d_ws, size_t ws_size,
                              hipStream_t stream) {
  const int*   ctx  = (const int*)d_in[0];
  const float* emb  = (const float*)d_in[1];
  const float* W    = (const float*)d_in[2];
  const float* U    = (const float*)d_in[3];
  const float* bias = (const float*)d_in[4];
  float* out = (float*)d_out;

  char* ws = (char*)d_ws;
  __hip_bfloat16* embb  = (__hip_bfloat16*)(ws + OFF_EMBB);
  __hip_bfloat16* Wt    = (__hip_bfloat16*)(ws + OFF_WT);
  __hip_bfloat16* Ut    = (__hip_bfloat16*)(ws + OFF_UT);
  __hip_bfloat16* hbuf  = (__hip_bfloat16*)(ws + OFF_HBUF);
  unsigned*       flags = (unsigned*)(ws + OFF_FLAGS);

  // flags must be zero every launch (graph replays do not re-poison ws)
  hipMemsetAsync(flags, 0, 4 * 8 * 16 * sizeof(unsigned), stream);

  prep_kernel<<<1024, 256, 0, stream>>>(emb, W, U, embb, Wt, Ut);
  lstm_kernel<<<32, 256, 0, stream>>>(ctx, bias, embb, Wt, Ut, hbuf, flags, out);
}

// Round 2
// 7851.797 us; speedup vs baseline: 1.3425x; 1.3425x over previous
//
#include <hip/hip_runtime.h>
#include <hip/hip_bf16.h>

// LSTM encoder: B=64, L=2048, D=256, 4D=1024, VOCAB=6000
// 32 persistent WGs = 4 row-groups(16 rows) x 8 col-WGs(32 d-channels).
// Weights [U;W] held permanently in VGPRs as MFMA B-fragments.
// Cross-WG h/flag exchange via sc0+sc1 (cache-bypassing, point-coherent)
// loads/stores -- NO agent fences, NO buffer_wbl2/inv per step.
// Per step: x-MFMAs -> flag spin -> h loads (sc0sc1) -> h-MFMAs ->
// gates via LDS -> elementwise (c,h in regs) -> h store (sc0sc1) ->
// barrier(drain) -> flag store -> out store (off critical path).

#define B_     64
#define L_     2048
#define D_     256
#define G4_    1024
#define VOCAB_ 6000

typedef short s16x8 __attribute__((ext_vector_type(8)));
typedef float f32x4 __attribute__((ext_vector_type(4)));

// ---- ws layout (bytes) ----
#define OFF_EMBB   0u                       // VOCAB*D bf16 = 3,072,000
#define OFF_WT     3072000u                 // 4D x D bf16 (W^T) = 524,288
#define OFF_UT     3596288u                 // 4D x D bf16 (U^T) = 524,288
#define OFF_HBUF   4120576u                 // 2 x (64 x 256) bf16 = 65,536
#define OFF_FLAGS  4186112u                 // 4 groups x 8 flags x 64B = 2048
#define WS_NEED    4188160u

__global__ void prep_kernel(const float* __restrict__ emb,
                            const float* __restrict__ W,
                            const float* __restrict__ U,
                            __hip_bfloat16* __restrict__ embb,
                            __hip_bfloat16* __restrict__ Wt,
                            __hip_bfloat16* __restrict__ Ut) {
  const int stride = gridDim.x * blockDim.x;
  const int i0 = blockIdx.x * blockDim.x + threadIdx.x;
  for (int i = i0; i < VOCAB_ * D_; i += stride)
    embb[i] = __float2bfloat16(emb[i]);
  for (int i = i0; i < D_ * G4_; i += stride) {
    int k = i >> 10;            // row in W/U (0..255)
    int n = i & (G4_ - 1);      // col (0..1023)
    Wt[n * D_ + k] = __float2bfloat16(W[i]);
    Ut[n * D_ + k] = __float2bfloat16(U[i]);
  }
}

// coherent (cache-bypassing) helpers ---------------------------------------
__device__ inline unsigned ld_coh_u32(const unsigned* p) {
  unsigned r;
  asm volatile("global_load_dword %0, %1, off sc0 sc1\n\t"
               "s_waitcnt vmcnt(0)"
               : "=v"(r) : "v"(p) : "memory");
  return r;
}
__device__ inline void st_coh_u32(unsigned* p, unsigned v) {
  asm volatile("global_store_dword %0, %1, off sc0 sc1"
               :: "v"(p), "v"(v) : "memory");
}

__device__ inline float fsigmoid(float x) { return 1.f / (1.f + __expf(-x)); }
__device__ inline float ftanh(float x)    { return 1.f - 2.f / (__expf(2.f * x) + 1.f); }

__global__ __launch_bounds__(256, 1)
void lstm_kernel(const int* __restrict__ ctx,
                 const float* __restrict__ bias,
                 const __hip_bfloat16* __restrict__ embb,
                 const __hip_bfloat16* __restrict__ Wt,
                 const __hip_bfloat16* __restrict__ Ut,
                 __hip_bfloat16* __restrict__ hbuf,
                 unsigned* __restrict__ flags,
                 float* __restrict__ out) {
  const int wg  = blockIdx.x;
  const int g   = wg & 3;        // row group: batch rows [g*16, g*16+16)
  const int cB  = wg >> 2;       // d-block: d in [cB*32, cB*32+32)
  const int tid = threadIdx.x;
  const int v   = tid >> 6;      // wave index == gate index (i,f,cand,o)
  const int l   = tid & 63;
  const int l15 = l & 15, lhi = l >> 4;

  __shared__ int   s_tok[2][16];
  __shared__ float s_g[4][16][33];   // [gate][row][d_local], +1 pad
  __shared__ float s_b[4][32];

  if (tid < 128) {
    int q = tid >> 5, dl = tid & 31;
    s_b[q][dl] = bias[q * D_ + cB * 32 + dl];
  }

  // ---- preload weight B-fragments: wave v owns gate v, 2 n-tiles of 16 cols.
  // B[k][n] frag layout: lane l holds k = kk*32 + (l>>4)*8 + j (j=0..7), n = n0 + (l&15).
  // kk 0..7 -> U (h part), kk 8..15 -> W (x part).
  s16x8 bfr[16][2];
  {
    const int nbase = v * D_ + cB * 32;
#pragma unroll
    for (int nt = 0; nt < 2; ++nt) {
      const int n = nbase + nt * 16 + l15;
      const __hip_bfloat16* up = Ut + n * D_ + lhi * 8;
      const __hip_bfloat16* wp = Wt + n * D_ + lhi * 8;
#pragma unroll
      for (int kk = 0; kk < 8; ++kk) {
        bfr[kk][nt]     = *(const s16x8*)(up + kk * 32);
        bfr[kk + 8][nt] = *(const s16x8*)(wp + kk * 32);
      }
    }
  }

  // elementwise ownership: thread -> (row em, d_local ed, ed+1)
  const int em = tid >> 4;
  const int ed = (tid & 15) * 2;
  float c0 = 0.f, c1 = 0.f, hp0 = 0.f, hp1 = 0.f;

  unsigned* myflags = flags + g * 8 * 16;   // 8 flags, 64B apart
  const int row0 = g * 16;

  if (tid < 16) s_tok[0][tid] = ctx[(row0 + tid) * L_];
  __syncthreads();

  for (int t = 0; t < L_; ++t) {
    const int cur = t & 1;

    // ---- x part (independent of h): A[m][k] = emb[tok[m]][k]
    const int tok = s_tok[cur][l15];
    const __hip_bfloat16* xp = embb + tok * D_ + lhi * 8;
    s16x8 af[8];
#pragma unroll
    for (int kk = 0; kk < 8; ++kk)
      af[kk] = *(const s16x8*)(xp + kk * 32);

    f32x4 acc0 = {0.f, 0.f, 0.f, 0.f}, acc1 = {0.f, 0.f, 0.f, 0.f};
#pragma unroll
    for (int kk = 0; kk < 8; ++kk) {
      acc0 = __builtin_amdgcn_mfma_f32_16x16x32_bf16(af[kk], bfr[kk + 8][0], acc0, 0, 0, 0);
      acc1 = __builtin_amdgcn_mfma_f32_16x16x32_bf16(af[kk], bfr[kk + 8][1], acc1, 0, 0, 0);
    }

    // ---- h part: wait for all 8 col-WGs of this group to publish h(t-1)
    if (t > 0) {
      const unsigned want = (unsigned)t;
      const unsigned* fp = myflags + (l & 7) * 16;
      while (true) {
        unsigned f = ld_coh_u32(fp);
        if (__all((int)(f >= want))) break;
      }
      const __hip_bfloat16* hp =
          hbuf + ((t - 1) & 1) * (B_ * D_) + (row0 + l15) * D_ + lhi * 8;
      s16x8 h0, h1, h2, h3, h4, h5, h6, h7;
      asm volatile(
          "global_load_dwordx4 %0, %8, off sc0 sc1\n\t"
          "global_load_dwordx4 %1, %8, off offset:64 sc0 sc1\n\t"
          "global_load_dwordx4 %2, %8, off offset:128 sc0 sc1\n\t"
          "global_load_dwordx4 %3, %8, off offset:192 sc0 sc1\n\t"
          "global_load_dwordx4 %4, %8, off offset:256 sc0 sc1\n\t"
          "global_load_dwordx4 %5, %8, off offset:320 sc0 sc1\n\t"
          "global_load_dwordx4 %6, %8, off offset:384 sc0 sc1\n\t"
          "global_load_dwordx4 %7, %8, off offset:448 sc0 sc1\n\t"
          "s_waitcnt vmcnt(0)"
          : "=&v"(h0), "=&v"(h1), "=&v"(h2), "=&v"(h3),
            "=&v"(h4), "=&v"(h5), "=&v"(h6), "=&v"(h7)
          : "v"(hp) : "memory");
#pragma unroll
      for (int kk = 0; kk < 8; ++kk) {
        s16x8 hf = (kk == 0) ? h0 : (kk == 1) ? h1 : (kk == 2) ? h2 : (kk == 3) ? h3
                 : (kk == 4) ? h4 : (kk == 5) ? h5 : (kk == 6) ? h6 : h7;
        acc0 = __builtin_amdgcn_mfma_f32_16x16x32_bf16(hf, bfr[kk][0], acc0, 0, 0, 0);
        acc1 = __builtin_amdgcn_mfma_f32_16x16x32_bf16(hf, bfr[kk][1], acc1, 0, 0, 0);
      }
    }

    // ---- gates to LDS (C/D layout: row=(l>>4)*4+r, col=l&15)
#pragma unroll
    for (int r = 0; r < 4; ++r) {
      s_g[v][lhi * 4 + r][l15]      = acc0[r];
      s_g[v][lhi * 4 + r][16 + l15] = acc1[r];
    }
    __syncthreads();   // (A) gates visible; prev-step s_g reads done

    // ---- elementwise LSTM update (2 elements per thread)
    {
      // prefetch next token (wave 0 only), consumed after barrier (B)
      if (tid < 16 && t + 1 < L_)
        s_tok[cur ^ 1][tid] = ctx[(row0 + tid) * L_ + t + 1];

      const int tokm = s_tok[cur][em];
      float gi0 = s_g[0][em][ed]     + s_b[0][ed];
      float gi1 = s_g[0][em][ed + 1] + s_b[0][ed + 1];
      float gf0 = s_g[1][em][ed]     + s_b[1][ed];
      float gf1 = s_g[1][em][ed + 1] + s_b[1][ed + 1];
      float gc0 = s_g[2][em][ed]     + s_b[2][ed];
      float gc1 = s_g[2][em][ed + 1] + s_b[2][ed + 1];
      float go0 = s_g[3][em][ed]     + s_b[3][ed];
      float go1 = s_g[3][em][ed + 1] + s_b[3][ed + 1];
      float i0 = fsigmoid(gi0), i1 = fsigmoid(gi1);
      float f0 = fsigmoid(gf0), f1 = fsigmoid(gf1);
      float o0 = fsigmoid(go0), o1 = fsigmoid(go1);
      float cn0 = f0 * c0 + i0 * ftanh(gc0);
      float cn1 = f1 * c1 + i1 * ftanh(gc1);
      float hn0 = o0 * ftanh(cn0);
      float hn1 = o1 * ftanh(cn1);
      const bool upd = (tokm != 0);
      c0  = upd ? cn0 : c0;   c1  = upd ? cn1 : c1;
      hp0 = upd ? hn0 : hp0;  hp1 = upd ? hn1 : hp1;

      // h store: coherent write-through (2 bf16 packed in 1 dword)
      const int orow = row0 + em;
      unsigned hv = ((unsigned)__bfloat16_as_ushort(__float2bfloat16(hp1)) << 16)
                  |  (unsigned)__bfloat16_as_ushort(__float2bfloat16(hp0));
      unsigned* hw = (unsigned*)(hbuf + cur * (B_ * D_) + orow * D_ + cB * 32 + ed);
      st_coh_u32(hw, hv);
    }

    __syncthreads();   // (B) drains all waves' h stores (compiler vmcnt(0))

    if (tid == 0)
      st_coh_u32(myflags + cB * 16, (unsigned)(t + 1));

    // ---- output store AFTER publish: off the inter-WG critical path
    {
      const int orow = row0 + em;
      float* op = out + ((size_t)orow * L_ + t) * D_ + cB * 32 + ed;
      op[0] = hp0;
      op[1] = hp1;
    }
  }
}

extern "C" void kernel_launch(void* const* d_in, const int* in_sizes, int n_in,
                              void* d_out, int out_size, void* d_ws, size_t ws_size,
                              hipStream_t stream) {
  const int*   ctx  = (const int*)d_in[0];
  const float* emb  = (const float*)d_in[1];
  const float* W    = (const float*)d_in[2];
  const float* U    = (const float*)d_in[3];
  const float* bias = (const float*)d_in[4];
  float* out = (float*)d_out;

  char* ws = (char*)d_ws;
  __hip_bfloat16* embb  = (__hip_bfloat16*)(ws + OFF_EMBB);
  __hip_bfloat16* Wt    = (__hip_bfloat16*)(ws + OFF_WT);
  __hip_bfloat16* Ut    = (__hip_bfloat16*)(ws + OFF_UT);
  __hip_bfloat16* hbuf  = (__hip_bfloat16*)(ws + OFF_HBUF);
  unsigned*       flags = (unsigned*)(ws + OFF_FLAGS);

  // flags must be zero every launch (graph replays do not re-poison ws)
  hipMemsetAsync(flags, 0, 4 * 8 * 16 * sizeof(unsigned), stream);

  prep_kernel<<<1024, 256, 0, stream>>>(emb, W, U, embb, Wt, Ut);
  lstm_kernel<<<32, 256, 0, stream>>>(ctx, bias, embb, Wt, Ut, hbuf, flags, out);
}

// Round 3
// 7722.257 us; speedup vs baseline: 1.3651x; 1.0168x over previous
//
#include <hip/hip_runtime.h>
#include <hip/hip_bf16.h>

// LSTM encoder: B=64, L=2048, D=256, 4D=1024, VOCAB=6000
// 32 persistent WGs = 4 row-groups(16 rows) x 8 col-WGs(32 d-channels).
// Weights [U;W] live permanently in VGPRs as MFMA B-fragments.
// Cross-WG h exchange: TAGGED 8B granules {2xbf16, step-tag} stored with one
// sc0sc1 dwordx2 (atomic 8B at the coherent point). Consumers poll the data
// itself (16 dwordx4 sc0sc1 loads, min-tag check) -- flag, h-load round trip,
// and all vmcnt drains are GONE. Only one raw s_barrier (lgkmcnt only) per
// step for the gate LDS exchange.

#define B_     64
#define L_     2048
#define D_     256
#define G4_    1024
#define VOCAB_ 6000

typedef short    s16x8 __attribute__((ext_vector_type(8)));
typedef float    f32x4 __attribute__((ext_vector_type(4)));
typedef unsigned u32x4 __attribute__((ext_vector_type(4)));
typedef unsigned u32x2 __attribute__((ext_vector_type(2)));

// ---- ws layout (bytes) ----
#define OFF_EMBB   0u                       // VOCAB*D bf16 = 3,072,000
#define OFF_WT     3072000u                 // 4D x D bf16 (W^T) = 524,288
#define OFF_UT     3596288u                 // 4D x D bf16 (U^T) = 524,288
#define OFF_HTAG   4120576u                 // 2 x 64 x 128 x 8B = 131,072
#define WS_NEED    4251648u

__global__ void prep_kernel(const float* __restrict__ emb,
                            const float* __restrict__ W,
                            const float* __restrict__ U,
                            __hip_bfloat16* __restrict__ embb,
                            __hip_bfloat16* __restrict__ Wt,
                            __hip_bfloat16* __restrict__ Ut) {
  const int stride = gridDim.x * blockDim.x;
  const int i0 = blockIdx.x * blockDim.x + threadIdx.x;
  for (int i = i0; i < VOCAB_ * D_; i += stride)
    embb[i] = __float2bfloat16(emb[i]);
  for (int i = i0; i < D_ * G4_; i += stride) {
    int k = i >> 10;            // row in W/U (0..255)
    int n = i & (G4_ - 1);      // col (0..1023)
    Wt[n * D_ + k] = __float2bfloat16(W[i]);
    Ut[n * D_ + k] = __float2bfloat16(U[i]);
  }
}

__device__ inline float fsigmoid(float x) { return 1.f / (1.f + __expf(-x)); }
__device__ inline float ftanh(float x)    { return 1.f - 2.f / (__expf(2.f * x) + 1.f); }

__global__ __launch_bounds__(256, 1)
void lstm_kernel(const int* __restrict__ ctx,
                 const float* __restrict__ bias,
                 const __hip_bfloat16* __restrict__ embb,
                 const __hip_bfloat16* __restrict__ Wt,
                 const __hip_bfloat16* __restrict__ Ut,
                 char* __restrict__ htag,        // tagged h buffer (byte ptr)
                 float* __restrict__ out) {
  const int wg  = blockIdx.x;
  const int g   = wg & 3;        // row group: batch rows [g*16, g*16+16)
  const int cB  = wg >> 2;       // d-block: d in [cB*32, cB*32+32)
  const int tid = threadIdx.x;
  const int v   = tid >> 6;      // wave index == gate index (i,f,cand,o)
  const int l   = tid & 63;
  const int l15 = l & 15, lhi = l >> 4;
  const int row0 = g * 16;

  __shared__ float s_g[4][16][33];   // [gate][row][d_local], +1 pad

  // elementwise ownership: thread -> (row em, d_local ed, ed+1)
  const int em = tid >> 4;
  const int ed = (tid & 15) * 2;

  // bias in registers (per-thread, for its 2 columns x 4 gates)
  float b0[4], b1[4];
#pragma unroll
  for (int q = 0; q < 4; ++q) {
    b0[q] = bias[q * D_ + cB * 32 + ed];
    b1[q] = bias[q * D_ + cB * 32 + ed + 1];
  }

  // ---- preload weight B-fragments: wave v owns gate v, 2 n-tiles of 16 cols.
  // B[k][n] frag: lane l holds k = kk*32 + (l>>4)*8 + j (j=0..7), n = n0 + (l&15).
  // kk 0..7 -> U (h part), kk 8..15 -> W (x part).
  s16x8 bfr[16][2];
  {
    const int nbase = v * D_ + cB * 32;
#pragma unroll
    for (int nt = 0; nt < 2; ++nt) {
      const int n = nbase + nt * 16 + l15;
      const __hip_bfloat16* up = Ut + n * D_ + lhi * 8;
      const __hip_bfloat16* wp = Wt + n * D_ + lhi * 8;
#pragma unroll
      for (int kk = 0; kk < 8; ++kk) {
        bfr[kk][nt]     = *(const s16x8*)(up + kk * 32);
        bfr[kk + 8][nt] = *(const s16x8*)(wp + kk * 32);
      }
    }
  }

  float c0 = 0.f, c1 = 0.f, hp0 = 0.f, hp1 = 0.f;

  // token prefetch (registers only)
  int tokx = ctx[(row0 + l15) * L_];     // row for x-gather (A-fragment)
  int tokm = ctx[(row0 + em) * L_];      // row for elementwise mask

  for (int t = 0; t < L_; ++t) {
    // ---- prefetch next tokens (off critical path)
    int tokx_n = 0, tokm_n = 0;
    if (t + 1 < L_) {
      tokx_n = ctx[(row0 + l15) * L_ + t + 1];
      tokm_n = ctx[(row0 + em) * L_ + t + 1];
    }

    // ---- x part (independent of h): A[m][k] = emb[tok[m]][k]
    const __hip_bfloat16* xp = embb + tokx * D_ + lhi * 8;
    s16x8 af0 = *(const s16x8*)(xp);
    s16x8 af1 = *(const s16x8*)(xp + 32);
    s16x8 af2 = *(const s16x8*)(xp + 64);
    s16x8 af3 = *(const s16x8*)(xp + 96);
    s16x8 af4 = *(const s16x8*)(xp + 128);
    s16x8 af5 = *(const s16x8*)(xp + 160);
    s16x8 af6 = *(const s16x8*)(xp + 192);
    s16x8 af7 = *(const s16x8*)(xp + 224);

    f32x4 acc0 = {0.f, 0.f, 0.f, 0.f}, acc1 = {0.f, 0.f, 0.f, 0.f};
    acc0 = __builtin_amdgcn_mfma_f32_16x16x32_bf16(af0, bfr[8][0],  acc0, 0, 0, 0);
    acc1 = __builtin_amdgcn_mfma_f32_16x16x32_bf16(af0, bfr[8][1],  acc1, 0, 0, 0);
    acc0 = __builtin_amdgcn_mfma_f32_16x16x32_bf16(af1, bfr[9][0],  acc0, 0, 0, 0);
    acc1 = __builtin_amdgcn_mfma_f32_16x16x32_bf16(af1, bfr[9][1],  acc1, 0, 0, 0);
    acc0 = __builtin_amdgcn_mfma_f32_16x16x32_bf16(af2, bfr[10][0], acc0, 0, 0, 0);
    acc1 = __builtin_amdgcn_mfma_f32_16x16x32_bf16(af2, bfr[10][1], acc1, 0, 0, 0);
    acc0 = __builtin_amdgcn_mfma_f32_16x16x32_bf16(af3, bfr[11][0], acc0, 0, 0, 0);
    acc1 = __builtin_amdgcn_mfma_f32_16x16x32_bf16(af3, bfr[11][1], acc1, 0, 0, 0);
    acc0 = __builtin_amdgcn_mfma_f32_16x16x32_bf16(af4, bfr[12][0], acc0, 0, 0, 0);
    acc1 = __builtin_amdgcn_mfma_f32_16x16x32_bf16(af4, bfr[12][1], acc1, 0, 0, 0);
    acc0 = __builtin_amdgcn_mfma_f32_16x16x32_bf16(af5, bfr[13][0], acc0, 0, 0, 0);
    acc1 = __builtin_amdgcn_mfma_f32_16x16x32_bf16(af5, bfr[13][1], acc1, 0, 0, 0);
    acc0 = __builtin_amdgcn_mfma_f32_16x16x32_bf16(af6, bfr[14][0], acc0, 0, 0, 0);
    acc1 = __builtin_amdgcn_mfma_f32_16x16x32_bf16(af6, bfr[14][1], acc1, 0, 0, 0);
    acc0 = __builtin_amdgcn_mfma_f32_16x16x32_bf16(af7, bfr[15][0], acc0, 0, 0, 0);
    acc1 = __builtin_amdgcn_mfma_f32_16x16x32_bf16(af7, bfr[15][1], acc1, 0, 0, 0);

    // ---- tagged h poll: load h(t-1) granules, tags must reach t.
    // lane reads row (row0+l15), kd = kk*16 + lhi*4 + (0..3)  (byte kk*128+lhi*32)
    {
      const unsigned want = (unsigned)t;
      const char* hp = htag + ((t + 1) & 1) * 65536 + (row0 + l15) * 1024 + lhi * 32;
      u32x4 q0, q1, q2, q3, q4, q5, q6, q7, q8, q9, qa, qb, qc, qd, qe, qf;
      while (true) {
        asm volatile(
            "global_load_dwordx4 %0, %16, off sc0 sc1\n\t"
            "global_load_dwordx4 %1, %16, off offset:16 sc0 sc1\n\t"
            "global_load_dwordx4 %2, %16, off offset:128 sc0 sc1\n\t"
            "global_load_dwordx4 %3, %16, off offset:144 sc0 sc1\n\t"
            "global_load_dwordx4 %4, %16, off offset:256 sc0 sc1\n\t"
            "global_load_dwordx4 %5, %16, off offset:272 sc0 sc1\n\t"
            "global_load_dwordx4 %6, %16, off offset:384 sc0 sc1\n\t"
            "global_load_dwordx4 %7, %16, off offset:400 sc0 sc1\n\t"
            "global_load_dwordx4 %8, %16, off offset:512 sc0 sc1\n\t"
            "global_load_dwordx4 %9, %16, off offset:528 sc0 sc1\n\t"
            "global_load_dwordx4 %10, %16, off offset:640 sc0 sc1\n\t"
            "global_load_dwordx4 %11, %16, off offset:656 sc0 sc1\n\t"
            "global_load_dwordx4 %12, %16, off offset:768 sc0 sc1\n\t"
            "global_load_dwordx4 %13, %16, off offset:784 sc0 sc1\n\t"
            "global_load_dwordx4 %14, %16, off offset:896 sc0 sc1\n\t"
            "global_load_dwordx4 %15, %16, off offset:912 sc0 sc1\n\t"
            "s_waitcnt vmcnt(0)"
            : "=&v"(q0), "=&v"(q1), "=&v"(q2), "=&v"(q3),
              "=&v"(q4), "=&v"(q5), "=&v"(q6), "=&v"(q7),
              "=&v"(q8), "=&v"(q9), "=&v"(qa), "=&v"(qb),
              "=&v"(qc), "=&v"(qd), "=&v"(qe), "=&v"(qf)
            : "v"(hp) : "memory");
        unsigned mn = q0.y;
#define MN_(Q) mn = (Q.y < mn ? Q.y : mn); mn = (Q.w < mn ? Q.w : mn)
        mn = (q0.w < mn ? q0.w : mn);
        MN_(q1); MN_(q2); MN_(q3); MN_(q4); MN_(q5); MN_(q6); MN_(q7);
        MN_(q8); MN_(q9); MN_(qa); MN_(qb); MN_(qc); MN_(qd); MN_(qe); MN_(qf);
#undef MN_
        if (__all((int)(mn >= want))) break;
      }
      // assemble h fragments from data dwords (x,z of each load) and MFMA
      union Cvt { unsigned u[4]; s16x8 v; };
#define HMFMA_(QA, QB, KK)                                              \
      { Cvt cv_; cv_.u[0] = QA.x; cv_.u[1] = QA.z;                      \
        cv_.u[2] = QB.x; cv_.u[3] = QB.z;                               \
        acc0 = __builtin_amdgcn_mfma_f32_16x16x32_bf16(cv_.v, bfr[KK][0], acc0, 0, 0, 0); \
        acc1 = __builtin_amdgcn_mfma_f32_16x16x32_bf16(cv_.v, bfr[KK][1], acc1, 0, 0, 0); }
      HMFMA_(q0, q1, 0); HMFMA_(q2, q3, 1); HMFMA_(q4, q5, 2); HMFMA_(q6, q7, 3);
      HMFMA_(q8, q9, 4); HMFMA_(qa, qb, 5); HMFMA_(qc, qd, 6); HMFMA_(qe, qf, 7);
#undef HMFMA_
    }

    // ---- gates to LDS (C/D layout: row=(l>>4)*4+r, col=l&15)
#pragma unroll
    for (int r = 0; r < 4; ++r) {
      s_g[v][lhi * 4 + r][l15]      = acc0[r];
      s_g[v][lhi * 4 + r][16 + l15] = acc1[r];
    }
    asm volatile("s_waitcnt lgkmcnt(0)" ::: "memory");
    __builtin_amdgcn_s_barrier();   // raw barrier: no vmcnt drain
    // (cross-step s_g WAR is gated by the tag poll: a wave re-writes s_g only
    //  after seeing all h tags of step t, which are stored after s_g reads.)

    // ---- elementwise LSTM update (2 elements per thread)
    {
      float gi0 = s_g[0][em][ed]     + b0[0];
      float gi1 = s_g[0][em][ed + 1] + b1[0];
      float gf0 = s_g[1][em][ed]     + b0[1];
      float gf1 = s_g[1][em][ed + 1] + b1[1];
      float gc0 = s_g[2][em][ed]     + b0[2];
      float gc1 = s_g[2][em][ed + 1] + b1[2];
      float go0 = s_g[3][em][ed]     + b0[3];
      float go1 = s_g[3][em][ed + 1] + b1[3];
      float i0 = fsigmoid(gi0), i1 = fsigmoid(gi1);
      float f0 = fsigmoid(gf0), f1 = fsigmoid(gf1);
      float o0 = fsigmoid(go0), o1 = fsigmoid(go1);
      float cn0 = f0 * c0 + i0 * ftanh(gc0);
      float cn1 = f1 * c1 + i1 * ftanh(gc1);
      float hn0 = o0 * ftanh(cn0);
      float hn1 = o1 * ftanh(cn1);
      const bool upd = (tokm != 0);
      c0  = upd ? cn0 : c0;   c1  = upd ? cn1 : c1;
      hp0 = upd ? hn0 : hp0;  hp1 = upd ? hn1 : hp1;

      // tagged h store: ONE atomic 8B granule {2xbf16, tag}, no drain needed
      const int orow = row0 + em;
      unsigned hv = ((unsigned)__bfloat16_as_ushort(__float2bfloat16(hp1)) << 16)
                  |  (unsigned)__bfloat16_as_ushort(__float2bfloat16(hp0));
      u32x2 hv2; hv2.x = hv; hv2.y = (unsigned)(t + 1);
      char* hw = htag + (t & 1) * 65536 + orow * 1024 + (cB * 16 + (ed >> 1)) * 8;
      asm volatile("global_store_dwordx2 %0, %1, off sc0 sc1"
                   :: "v"(hw), "v"(hv2) : "memory");

      // output store (fire-and-forget, off the inter-WG critical path)
      float* op = out + ((size_t)orow * L_ + t) * D_ + cB * 32 + ed;
      op[0] = hp0;
      op[1] = hp1;
    }

    tokx = tokx_n;
    tokm = tokm_n;
  }
}

extern "C" void kernel_launch(void* const* d_in, const int* in_sizes, int n_in,
                              void* d_out, int out_size, void* d_ws, size_t ws_size,
                              hipStream_t stream) {
  const int*   ctx  = (const int*)d_in[0];
  const float* emb  = (const float*)d_in[1];
  const float* W    = (const float*)d_in[2];
  const float* U    = (const float*)d_in[3];
  const float* bias = (const float*)d_in[4];
  float* out = (float*)d_out;

  char* ws = (char*)d_ws;
  __hip_bfloat16* embb = (__hip_bfloat16*)(ws + OFF_EMBB);
  __hip_bfloat16* Wt   = (__hip_bfloat16*)(ws + OFF_WT);
  __hip_bfloat16* Ut   = (__hip_bfloat16*)(ws + OFF_UT);
  char*           htag = ws + OFF_HTAG;

  // tags must start at 0 every launch (graph replays don't re-poison ws);
  // tag 0 == "h(-1)=0 ready", so t=0 needs no special case.
  hipMemsetAsync(htag, 0, 131072, stream);

  prep_kernel<<<1024, 256, 0, stream>>>(emb, W, U, embb, Wt, Ut);
  lstm_kernel<<<32, 256, 0, stream>>>(ctx, bias, embb, Wt, Ut, htag, out);
}